// Round 21
// baseline (45.840 us; speedup 1.0000x reference)
//
#include <hip/hip_runtime.h>
#include <stdint.h>

typedef float f32x2 __attribute__((ext_vector_type(2)));
typedef float f32x4 __attribute__((ext_vector_type(4)));
typedef uint32_t u32x4 __attribute__((ext_vector_type(4)));
typedef short s16x8 __attribute__((ext_vector_type(8)));

#define BB   8
#define NN   2048
#define FIN  128
#define FOUT 64

__device__ __forceinline__ uint32_t cvt_pk_bf16(float lo, float hi) {
  uint32_t r;
  asm("v_cvt_pk_bf16_f32 %0, %1, %2" : "=v"(r) : "v"(lo), "v"(hi));
  return r;
}

__device__ __forceinline__ s16x8 mk_s16x8(uint32_t a, uint32_t b, uint32_t c, uint32_t d) {
  union { uint32_t u[4]; s16x8 v; } x;
  x.u[0] = a; x.u[1] = b; x.u[2] = c; x.u[3] = d;
  return x.v;
}

// ---------------------------------------------------------------------------
// Kernel 1 (R1 lineage, proven): hidden = h @ W -> hidT [b][f][n] bf16; s1,s2.
// ---------------------------------------------------------------------------
__global__ void k1_hidden(const float* __restrict__ h, const float* __restrict__ W,
                          const float* __restrict__ attw, ushort* __restrict__ hidT,
                          float* __restrict__ s1, float* __restrict__ s2) {
  __shared__ ushort wlds[FOUT * 136];
  const int tid = threadIdx.x;

  for (int idx = tid; idx < FIN * FOUT; idx += 256) {
    int k = idx >> 6, c = idx & 63;
    wlds[c * 136 + k] = (ushort)(cvt_pk_bf16(W[idx], 0.f) & 0xffffu);
  }
  __syncthreads();

  const int bid = ((blockIdx.x & 7) << 5) | (blockIdx.x >> 3);
  const int lane = tid & 63, wid = tid >> 6;
  const int q = lane & 15, g = lane >> 4;
  const int wrow0 = bid * 64 + wid * 16;
  const int b  = wrow0 >> 11;
  const int n0 = wrow0 & (NN - 1);

  const float* hrow = h + (size_t)(wrow0 + q) * FIN + 8 * g;

  f32x4 acc[4];
  #pragma unroll
  for (int nt = 0; nt < 4; ++nt) acc[nt] = {0.f, 0.f, 0.f, 0.f};

  #pragma unroll
  for (int kk = 0; kk < 4; ++kk) {
    f32x4 h0 = *(const f32x4*)(hrow + 32 * kk);
    f32x4 h1 = *(const f32x4*)(hrow + 32 * kk + 4);
    s16x8 A = mk_s16x8(cvt_pk_bf16(h0[0], h0[1]), cvt_pk_bf16(h0[2], h0[3]),
                       cvt_pk_bf16(h1[0], h1[1]), cvt_pk_bf16(h1[2], h1[3]));
    #pragma unroll
    for (int nt = 0; nt < 4; ++nt) {
      s16x8 Bf = *(const s16x8*)(&wlds[(nt * 16 + q) * 136 + 32 * kk + 8 * g]);
      acc[nt] = __builtin_amdgcn_mfma_f32_16x16x32_bf16(A, Bf, acc[nt], 0, 0, 0);
    }
  }

  float a1v[4], a2v[4];
  #pragma unroll
  for (int nt = 0; nt < 4; ++nt) {
    a1v[nt] = attw[nt * 16 + q];
    a2v[nt] = attw[64 + nt * 16 + q];
  }
  float p1[4], p2[4];
  #pragma unroll
  for (int r = 0; r < 4; ++r) {
    float v1 = 0.f, v2 = 0.f;
    #pragma unroll
    for (int nt = 0; nt < 4; ++nt) { v1 += acc[nt][r] * a1v[nt]; v2 += acc[nt][r] * a2v[nt]; }
    #pragma unroll
    for (int m = 1; m < 16; m <<= 1) { v1 += __shfl_xor(v1, m, 64); v2 += __shfl_xor(v2, m, 64); }
    p1[r] = v1; p2[r] = v2;
  }
  if (q < 4) {
    int gr = wrow0 + 4 * g + q;
    float v1 = (q == 0) ? p1[0] : (q == 1) ? p1[1] : (q == 2) ? p1[2] : p1[3];
    float v2 = (q == 0) ? p2[0] : (q == 1) ? p2[1] : (q == 2) ? p2[2] : p2[3];
    s1[gr] = v1; s2[gr] = v2;
  }

  #pragma unroll
  for (int nt = 0; nt < 4; ++nt) {
    uint32_t lo = cvt_pk_bf16(acc[nt][0], acc[nt][1]);
    uint32_t hi = cvt_pk_bf16(acc[nt][2], acc[nt][3]);
    *(uint2*)(hidT + ((size_t)b * FOUT + nt * 16 + q) * NN + n0 + 4 * g) = make_uint2(lo, hi);
  }
}

// ---------------------------------------------------------------------------
// kF v5 (bisect): R20 minus the MFMA-lsum (restored R19 shuffle-lsum).
// Keeps: 2-deep named A/B register pipeline + nontemporal adj loads.
// grid 512 x 512 thr; 16 chunks of 128 j; LDS 41.4KB.
// ---------------------------------------------------------------------------
__global__ __launch_bounds__(512, 4) void kF(
    const float* __restrict__ adj, const ushort* __restrict__ hidT,
    const float* __restrict__ s1g, const float* __restrict__ s2g,
    float* __restrict__ out) {
  __shared__ __align__(16) char smem[41472];
  float* s2l   = (float*)(smem + 32768);
  float* partl = (float*)(smem + 40960);

  const int tid = threadIdx.x;
  // XCD swizzle: 512 blocks, XCD x <- 64 contiguous = batch x
  const int sb = ((blockIdx.x & 7) << 6) | (blockIdx.x >> 3);
  const int b  = sb >> 6;
  const int i0 = (sb & 63) << 5;

  const int lane = tid & 63, wid = tid >> 6;
  const int q = lane & 15, g = lane >> 4;
  const int rg = wid >> 2, jw = wid & 3;

  // s2 stage (once, 8KB)
  *(f32x4*)(s2l + tid * 4) = *(const f32x4*)(s2g + b * NN + tid * 4);
  const float s1r = s1g[b * NN + i0 + rg * 16 + q];

  const float* adjB = adj + ((size_t)(b * NN + i0 + wid)) * NN + lane * 2;
  const int f0 = tid >> 4, sl = tid & 15;
  const ushort* hBp = hidT + ((size_t)(b * FOUT + f0)) * NN + sl * 8;

  // two named register sets (rule #20: no runtime-indexed arrays)
  f32x2 aA0, aA1, aA2, aA3; u32x4 hA0, hA1;
  f32x2 aB0, aB1, aB2, aB3; u32x4 hB0, hB1;

#define LOAD_SET(a0_,a1_,a2_,a3_,h0_,h1_,cc) do {                             \
    const float* p_ = adjB + (cc) * 128;                                      \
    a0_ = __builtin_nontemporal_load((const f32x2*)(p_));                     \
    a1_ = __builtin_nontemporal_load((const f32x2*)(p_ + (size_t) 8 * NN));   \
    a2_ = __builtin_nontemporal_load((const f32x2*)(p_ + (size_t)16 * NN));   \
    a3_ = __builtin_nontemporal_load((const f32x2*)(p_ + (size_t)24 * NN));   \
    const ushort* q_ = hBp + (cc) * 128;                                      \
    h0_ = *(const u32x4*)(q_);                                                \
    h1_ = *(const u32x4*)(q_ + (size_t)32 * NN);                              \
  } while (0)

#define DSW_SET(a0_,a1_,a2_,a3_,h0_,h1_) do {                                 \
    const int aw = lane * 8;                                                  \
    *(f32x2*)(smem + (wid     ) * 512 + (aw ^ (((wid     ) & 7) << 4))) = a0_;\
    *(f32x2*)(smem + (wid +  8) * 512 + (aw ^ (((wid +  8) & 7) << 4))) = a1_;\
    *(f32x2*)(smem + (wid + 16) * 512 + (aw ^ (((wid + 16) & 7) << 4))) = a2_;\
    *(f32x2*)(smem + (wid + 24) * 512 + (aw ^ (((wid + 24) & 7) << 4))) = a3_;\
    char* d_ = smem + 16384;                                                  \
    const int hw = (sl << 4) ^ ((f0 & 7) << 4);                               \
    *(u32x4*)(d_ + (f0     ) * 256 + hw) = h0_;                               \
    *(u32x4*)(d_ + (f0 + 32) * 256 + hw) = h1_;                               \
  } while (0)

  // prologue: A <- chunk0 (staged), B <- chunk1 (held)
  LOAD_SET(aA0, aA1, aA2, aA3, hA0, hA1, 0);
  LOAD_SET(aB0, aB1, aB2, aB3, hB0, hB1, 1);
  DSW_SET(aA0, aA1, aA2, aA3, hA0, hA1);
  __syncthreads();

  f32x4 acc0 = {0,0,0,0}, acc1 = {0,0,0,0}, acc2 = {0,0,0,0}, acc3 = {0,0,0,0};
  float lsum = 0.f;
  const int xr = (q & 7) << 4;
  const int arow = rg * 16 + q;
  const char* hL = smem + 16384;

  #pragma unroll
  for (int c = 0; c < 16; ++c) {
    // 2-deep: issue chunk c+2 into the set freed by last DSW
    if (c + 2 < 16) {
      if ((c & 1) == 0) LOAD_SET(aA0, aA1, aA2, aA3, hA0, hA1, c + 2);
      else              LOAD_SET(aB0, aB1, aB2, aB3, hB0, hB1, c + 2);
    }

    {
      const int jb = jw * 128 + g * 32;
      f32x4 av0 = *(const f32x4*)(smem + arow * 512 + ((jb     ) ^ xr));
      f32x4 av1 = *(const f32x4*)(smem + arow * 512 + ((jb + 16) ^ xr));
      const int jl = jw * 32 + 8 * g;
      f32x4 t0 = *(const f32x4*)(s2l + c * 128 + jl);
      f32x4 t1 = *(const f32x4*)(s2l + c * 128 + jl + 4);
      const int hb_ = (jw * 64 + g * 16) ^ xr;
      u32x4 b0 = *(const u32x4*)(hL + (( 0 + q) << 8) + hb_);
      u32x4 b1 = *(const u32x4*)(hL + ((16 + q) << 8) + hb_);
      u32x4 b2 = *(const u32x4*)(hL + ((32 + q) << 8) + hb_);
      u32x4 b3 = *(const u32x4*)(hL + ((48 + q) << 8) + hb_);

      // p = adj * exp(leakyrelu(s1+s2));  adj is exactly 0 or 1
      float e0 = s1r + t0[0], e1 = s1r + t0[1], e2 = s1r + t0[2], e3 = s1r + t0[3];
      float e4 = s1r + t1[0], e5 = s1r + t1[1], e6 = s1r + t1[2], e7 = s1r + t1[3];
      float p0 = av0[0] * __expf(fmaxf(e0, 0.2f * e0));
      float p1 = av0[1] * __expf(fmaxf(e1, 0.2f * e1));
      float p2 = av0[2] * __expf(fmaxf(e2, 0.2f * e2));
      float p3 = av0[3] * __expf(fmaxf(e3, 0.2f * e3));
      float p4 = av1[0] * __expf(fmaxf(e4, 0.2f * e4));
      float p5 = av1[1] * __expf(fmaxf(e5, 0.2f * e5));
      float p6 = av1[2] * __expf(fmaxf(e6, 0.2f * e6));
      float p7 = av1[3] * __expf(fmaxf(e7, 0.2f * e7));
      lsum += ((p0 + p1) + (p2 + p3)) + ((p4 + p5) + (p6 + p7));

      s16x8 A = mk_s16x8(cvt_pk_bf16(p0, p1), cvt_pk_bf16(p2, p3),
                         cvt_pk_bf16(p4, p5), cvt_pk_bf16(p6, p7));
      union { u32x4 u; s16x8 v; } w0, w1, w2, w3;
      w0.u = b0; w1.u = b1; w2.u = b2; w3.u = b3;
      acc0 = __builtin_amdgcn_mfma_f32_16x16x32_bf16(A, w0.v, acc0, 0, 0, 0);
      acc1 = __builtin_amdgcn_mfma_f32_16x16x32_bf16(A, w1.v, acc1, 0, 0, 0);
      acc2 = __builtin_amdgcn_mfma_f32_16x16x32_bf16(A, w2.v, acc2, 0, 0, 0);
      acc3 = __builtin_amdgcn_mfma_f32_16x16x32_bf16(A, w3.v, acc3, 0, 0, 0);
    }

    __syncthreads();                       // reads of chunk c done
    if (c + 1 < 16) {
      if ((c & 1) == 0) DSW_SET(aB0, aB1, aB2, aB3, hB0, hB1);
      else              DSW_SET(aA0, aA1, aA2, aA3, hA0, hA1);
      __syncthreads();                     // stage c+1 visible
    }
  }

  // lsum: combine g-groups (same row q)  -- R19 proven path
  lsum += __shfl_xor(lsum, 16, 64);
  lsum += __shfl_xor(lsum, 32, 64);
  if (lane < 16) partl[jw * 32 + rg * 16 + lane] = lsum;

  // per-wave partials -> part (aliases adjL+HL; last loop barrier protects)
  float* part = (float*)smem;   // [4 jw][32 row][64 col] = 32KB
  #pragma unroll
  for (int r = 0; r < 4; ++r) {
    const int il = rg * 16 + 4 * g + r;
    part[(jw * 32 + il) * 64 +  0 + q] = acc0[r];
    part[(jw * 32 + il) * 64 + 16 + q] = acc1[r];
    part[(jw * 32 + il) * 64 + 32 + q] = acc2[r];
    part[(jw * 32 + il) * 64 + 48 + q] = acc3[r];
  }
  __syncthreads();

  // combine 4 j-quarters, normalize, ELU, write 32x64 outputs
  #pragma unroll
  for (int k = 0; k < 4; ++k) {
    const int idx = tid + 512 * k;
    const int row = idx >> 6, col = idx & 63;
    float v  = (part[(0 * 32 + row) * 64 + col] + part[(1 * 32 + row) * 64 + col]) +
               (part[(2 * 32 + row) * 64 + col] + part[(3 * 32 + row) * 64 + col]);
    float li = (partl[0 * 32 + row] + partl[1 * 32 + row]) +
               (partl[2 * 32 + row] + partl[3 * 32 + row]);
    float hp = v / li;
    out[(size_t)(b * NN + i0 + row) * 64 + col] = (hp > 0.f) ? hp : expm1f(hp);
  }
}

extern "C" void kernel_launch(void* const* d_in, const int* in_sizes, int n_in,
                              void* d_out, int out_size, void* d_ws, size_t ws_size,
                              hipStream_t stream) {
  const float* h    = (const float*)d_in[0];
  const float* adj  = (const float*)d_in[1];
  const float* W    = (const float*)d_in[2];
  const float* attw = (const float*)d_in[3];
  float* out = (float*)d_out;

  char* ws = (char*)d_ws;
  ushort* hidT = (ushort*)ws;                                   // 2 MB
  float*  s1   = (float*)(ws + (2u << 20));                     // 64 KB
  float*  s2   = (float*)(ws + (2u << 20) + (64u << 10));       // 64 KB

  hipLaunchKernelGGL(k1_hidden, dim3(256), dim3(256), 0, stream, h, W, attw, hidT, s1, s2);
  hipLaunchKernelGGL(kF, dim3(512), dim3(512), 0, stream, adj, hidT, s1, s2, out);
}

// Round 22
// 40.045 us; speedup vs baseline: 1.1447x; 1.1447x over previous
//
#include <hip/hip_runtime.h>
#include <stdint.h>

typedef float f32x2 __attribute__((ext_vector_type(2)));
typedef float f32x4 __attribute__((ext_vector_type(4)));
typedef uint32_t u32x4 __attribute__((ext_vector_type(4)));
typedef short s16x8 __attribute__((ext_vector_type(8)));

#define BB   8
#define NN   2048
#define FIN  128
#define FOUT 64

__device__ __forceinline__ uint32_t cvt_pk_bf16(float lo, float hi) {
  uint32_t r;
  asm("v_cvt_pk_bf16_f32 %0, %1, %2" : "=v"(r) : "v"(lo), "v"(hi));
  return r;
}

__device__ __forceinline__ s16x8 mk_s16x8(uint32_t a, uint32_t b, uint32_t c, uint32_t d) {
  union { uint32_t u[4]; s16x8 v; } x;
  x.u[0] = a; x.u[1] = b; x.u[2] = c; x.u[3] = d;
  return x.v;
}

// ---------------------------------------------------------------------------
// Kernel 1 (R1 lineage, proven): hidden = h @ W -> hidT [b][f][n] bf16; s1,s2.
// ---------------------------------------------------------------------------
__global__ void k1_hidden(const float* __restrict__ h, const float* __restrict__ W,
                          const float* __restrict__ attw, ushort* __restrict__ hidT,
                          float* __restrict__ s1, float* __restrict__ s2) {
  __shared__ ushort wlds[FOUT * 136];
  const int tid = threadIdx.x;

  for (int idx = tid; idx < FIN * FOUT; idx += 256) {
    int k = idx >> 6, c = idx & 63;
    wlds[c * 136 + k] = (ushort)(cvt_pk_bf16(W[idx], 0.f) & 0xffffu);
  }
  __syncthreads();

  const int bid = ((blockIdx.x & 7) << 5) | (blockIdx.x >> 3);
  const int lane = tid & 63, wid = tid >> 6;
  const int q = lane & 15, g = lane >> 4;
  const int wrow0 = bid * 64 + wid * 16;
  const int b  = wrow0 >> 11;
  const int n0 = wrow0 & (NN - 1);

  const float* hrow = h + (size_t)(wrow0 + q) * FIN + 8 * g;

  f32x4 acc[4];
  #pragma unroll
  for (int nt = 0; nt < 4; ++nt) acc[nt] = {0.f, 0.f, 0.f, 0.f};

  #pragma unroll
  for (int kk = 0; kk < 4; ++kk) {
    f32x4 h0 = *(const f32x4*)(hrow + 32 * kk);
    f32x4 h1 = *(const f32x4*)(hrow + 32 * kk + 4);
    s16x8 A = mk_s16x8(cvt_pk_bf16(h0[0], h0[1]), cvt_pk_bf16(h0[2], h0[3]),
                       cvt_pk_bf16(h1[0], h1[1]), cvt_pk_bf16(h1[2], h1[3]));
    #pragma unroll
    for (int nt = 0; nt < 4; ++nt) {
      s16x8 Bf = *(const s16x8*)(&wlds[(nt * 16 + q) * 136 + 32 * kk + 8 * g]);
      acc[nt] = __builtin_amdgcn_mfma_f32_16x16x32_bf16(A, Bf, acc[nt], 0, 0, 0);
    }
  }

  float a1v[4], a2v[4];
  #pragma unroll
  for (int nt = 0; nt < 4; ++nt) {
    a1v[nt] = attw[nt * 16 + q];
    a2v[nt] = attw[64 + nt * 16 + q];
  }
  float p1[4], p2[4];
  #pragma unroll
  for (int r = 0; r < 4; ++r) {
    float v1 = 0.f, v2 = 0.f;
    #pragma unroll
    for (int nt = 0; nt < 4; ++nt) { v1 += acc[nt][r] * a1v[nt]; v2 += acc[nt][r] * a2v[nt]; }
    #pragma unroll
    for (int m = 1; m < 16; m <<= 1) { v1 += __shfl_xor(v1, m, 64); v2 += __shfl_xor(v2, m, 64); }
    p1[r] = v1; p2[r] = v2;
  }
  if (q < 4) {
    int gr = wrow0 + 4 * g + q;
    float v1 = (q == 0) ? p1[0] : (q == 1) ? p1[1] : (q == 2) ? p1[2] : p1[3];
    float v2 = (q == 0) ? p2[0] : (q == 1) ? p2[1] : (q == 2) ? p2[2] : p2[3];
    s1[gr] = v1; s2[gr] = v2;
  }

  #pragma unroll
  for (int nt = 0; nt < 4; ++nt) {
    uint32_t lo = cvt_pk_bf16(acc[nt][0], acc[nt][1]);
    uint32_t hi = cvt_pk_bf16(acc[nt][2], acc[nt][3]);
    *(uint2*)(hidT + ((size_t)b * FOUT + nt * 16 + q) * NN + n0 + 4 * g) = make_uint2(lo, hi);
  }
}

// ---------------------------------------------------------------------------
// kF v6: FUSED adj-stream + softmax + PV with LDS DOUBLE-BUFFER and ONE
// barrier per chunk.  Iteration c: issue loads(c+1) -> compute from buf[c&1]
// -> DSW(c+1) into buf[(c+1)&1] (no overlap with buf[c&1] readers) -> sync.
// End-of-iteration barrier separates generation c-1 readers from c writers.
// LDS: buf0 @0 (adjL 16KB + HL 16KB), buf1 @32768, s2l 8KB @65536,
// partl 512B @73728 = 74.2KB -> 2 blocks/CU.  R19 numerics verbatim.
// ---------------------------------------------------------------------------
__global__ __launch_bounds__(512, 4) void kF(
    const float* __restrict__ adj, const ushort* __restrict__ hidT,
    const float* __restrict__ s1g, const float* __restrict__ s2g,
    float* __restrict__ out) {
  __shared__ __align__(16) char smem[74240];
  float* s2l   = (float*)(smem + 65536);
  float* partl = (float*)(smem + 73728);

  const int tid = threadIdx.x;
  // XCD swizzle: 512 blocks, XCD x <- 64 contiguous = batch x
  const int sb = ((blockIdx.x & 7) << 6) | (blockIdx.x >> 3);
  const int b  = sb >> 6;
  const int i0 = (sb & 63) << 5;

  const int lane = tid & 63, wid = tid >> 6;
  const int q = lane & 15, g = lane >> 4;
  const int rg = wid >> 2, jw = wid & 3;

  // s2 stage (once, 8KB)
  *(f32x4*)(s2l + tid * 4) = *(const f32x4*)(s2g + b * NN + tid * 4);
  const float s1r = s1g[b * NN + i0 + rg * 16 + q];

  const float* adjB = adj + ((size_t)(b * NN + i0 + wid)) * NN + lane * 2;
  const int f0 = tid >> 4, sl = tid & 15;
  const ushort* hBp = hidT + ((size_t)(b * FOUT + f0)) * NN + sl * 8;

  f32x2 a0, a1, a2, a3; u32x4 h0v, h1v;

#define LOADC(cc) do {                                                        \
    const float* p_ = adjB + (cc) * 128;                                      \
    a0 = *(const f32x2*)(p_);                                                 \
    a1 = *(const f32x2*)(p_ + (size_t) 8 * NN);                               \
    a2 = *(const f32x2*)(p_ + (size_t)16 * NN);                               \
    a3 = *(const f32x2*)(p_ + (size_t)24 * NN);                               \
    const ushort* q_ = hBp + (cc) * 128;                                      \
    h0v = *(const u32x4*)(q_);                                                \
    h1v = *(const u32x4*)(q_ + (size_t)32 * NN);                              \
  } while (0)

#define DSWC(B_) do {                                                         \
    char* db = smem + (B_) * 32768;                                           \
    const int aw = lane * 8;                                                  \
    *(f32x2*)(db + (wid     ) * 512 + (aw ^ (((wid     ) & 7) << 4))) = a0;   \
    *(f32x2*)(db + (wid +  8) * 512 + (aw ^ (((wid +  8) & 7) << 4))) = a1;   \
    *(f32x2*)(db + (wid + 16) * 512 + (aw ^ (((wid + 16) & 7) << 4))) = a2;   \
    *(f32x2*)(db + (wid + 24) * 512 + (aw ^ (((wid + 24) & 7) << 4))) = a3;   \
    char* d_ = db + 16384;                                                    \
    const int hw = (sl << 4) ^ ((f0 & 7) << 4);                               \
    *(u32x4*)(d_ + (f0     ) * 256 + hw) = h0v;                               \
    *(u32x4*)(d_ + (f0 + 32) * 256 + hw) = h1v;                               \
  } while (0)

  // prologue: stage chunk 0 into buf0
  LOADC(0);
  DSWC(0);
  __syncthreads();

  f32x4 acc0 = {0,0,0,0}, acc1 = {0,0,0,0}, acc2 = {0,0,0,0}, acc3 = {0,0,0,0};
  float lsum = 0.f;
  const int xr = (q & 7) << 4;
  const int arow = rg * 16 + q;

  #pragma unroll
  for (int c = 0; c < 16; ++c) {
    if (c < 15) LOADC(c + 1);              // in flight during compute(c)

    {
      const char* tb = smem + (c & 1) * 32768;
      const char* hL = tb + 16384;
      const int jb = jw * 128 + g * 32;
      f32x4 av0 = *(const f32x4*)(tb + arow * 512 + ((jb     ) ^ xr));
      f32x4 av1 = *(const f32x4*)(tb + arow * 512 + ((jb + 16) ^ xr));
      const int jl = jw * 32 + 8 * g;
      f32x4 t0 = *(const f32x4*)(s2l + c * 128 + jl);
      f32x4 t1 = *(const f32x4*)(s2l + c * 128 + jl + 4);
      const int hb_ = (jw * 64 + g * 16) ^ xr;
      u32x4 b0 = *(const u32x4*)(hL + (( 0 + q) << 8) + hb_);
      u32x4 b1 = *(const u32x4*)(hL + ((16 + q) << 8) + hb_);
      u32x4 b2 = *(const u32x4*)(hL + ((32 + q) << 8) + hb_);
      u32x4 b3 = *(const u32x4*)(hL + ((48 + q) << 8) + hb_);

      // p = adj * exp(leakyrelu(s1+s2));  adj is exactly 0 or 1
      float e0 = s1r + t0[0], e1 = s1r + t0[1], e2 = s1r + t0[2], e3 = s1r + t0[3];
      float e4 = s1r + t1[0], e5 = s1r + t1[1], e6 = s1r + t1[2], e7 = s1r + t1[3];
      float p0 = av0[0] * __expf(fmaxf(e0, 0.2f * e0));
      float p1 = av0[1] * __expf(fmaxf(e1, 0.2f * e1));
      float p2 = av0[2] * __expf(fmaxf(e2, 0.2f * e2));
      float p3 = av0[3] * __expf(fmaxf(e3, 0.2f * e3));
      float p4 = av1[0] * __expf(fmaxf(e4, 0.2f * e4));
      float p5 = av1[1] * __expf(fmaxf(e5, 0.2f * e5));
      float p6 = av1[2] * __expf(fmaxf(e6, 0.2f * e6));
      float p7 = av1[3] * __expf(fmaxf(e7, 0.2f * e7));
      lsum += ((p0 + p1) + (p2 + p3)) + ((p4 + p5) + (p6 + p7));

      s16x8 A = mk_s16x8(cvt_pk_bf16(p0, p1), cvt_pk_bf16(p2, p3),
                         cvt_pk_bf16(p4, p5), cvt_pk_bf16(p6, p7));
      union { u32x4 u; s16x8 v; } w0, w1, w2, w3;
      w0.u = b0; w1.u = b1; w2.u = b2; w3.u = b3;
      acc0 = __builtin_amdgcn_mfma_f32_16x16x32_bf16(A, w0.v, acc0, 0, 0, 0);
      acc1 = __builtin_amdgcn_mfma_f32_16x16x32_bf16(A, w1.v, acc1, 0, 0, 0);
      acc2 = __builtin_amdgcn_mfma_f32_16x16x32_bf16(A, w2.v, acc2, 0, 0, 0);
      acc3 = __builtin_amdgcn_mfma_f32_16x16x32_bf16(A, w3.v, acc3, 0, 0, 0);
    }

    if (c < 15) DSWC((c + 1) & 1);         // write into the OTHER buffer
    __syncthreads();                       // one barrier per chunk
  }

  // lsum: combine g-groups (same row q)  -- proven shuffle path
  lsum += __shfl_xor(lsum, 16, 64);
  lsum += __shfl_xor(lsum, 32, 64);
  if (lane < 16) partl[jw * 32 + rg * 16 + lane] = lsum;

  // per-wave partials -> part (aliases buf0; final loop barrier protects)
  float* part = (float*)smem;   // [4 jw][32 row][64 col] = 32KB
  #pragma unroll
  for (int r = 0; r < 4; ++r) {
    const int il = rg * 16 + 4 * g + r;
    part[(jw * 32 + il) * 64 +  0 + q] = acc0[r];
    part[(jw * 32 + il) * 64 + 16 + q] = acc1[r];
    part[(jw * 32 + il) * 64 + 32 + q] = acc2[r];
    part[(jw * 32 + il) * 64 + 48 + q] = acc3[r];
  }
  __syncthreads();

  // combine 4 j-quarters, normalize, ELU, write 32x64 outputs
  #pragma unroll
  for (int k = 0; k < 4; ++k) {
    const int idx = tid + 512 * k;
    const int row = idx >> 6, col = idx & 63;
    float v  = (part[(0 * 32 + row) * 64 + col] + part[(1 * 32 + row) * 64 + col]) +
               (part[(2 * 32 + row) * 64 + col] + part[(3 * 32 + row) * 64 + col]);
    float li = (partl[0 * 32 + row] + partl[1 * 32 + row]) +
               (partl[2 * 32 + row] + partl[3 * 32 + row]);
    float hp = v / li;
    out[(size_t)(b * NN + i0 + row) * 64 + col] = (hp > 0.f) ? hp : expm1f(hp);
  }
}

extern "C" void kernel_launch(void* const* d_in, const int* in_sizes, int n_in,
                              void* d_out, int out_size, void* d_ws, size_t ws_size,
                              hipStream_t stream) {
  const float* h    = (const float*)d_in[0];
  const float* adj  = (const float*)d_in[1];
  const float* W    = (const float*)d_in[2];
  const float* attw = (const float*)d_in[3];
  float* out = (float*)d_out;

  char* ws = (char*)d_ws;
  ushort* hidT = (ushort*)ws;                                   // 2 MB
  float*  s1   = (float*)(ws + (2u << 20));                     // 64 KB
  float*  s2   = (float*)(ws + (2u << 20) + (64u << 10));       // 64 KB

  hipLaunchKernelGGL(k1_hidden, dim3(256), dim3(256), 0, stream, h, W, attw, hidT, s1, s2);
  hipLaunchKernelGGL(kF, dim3(512), dim3(512), 0, stream, adj, hidT, s1, s2, out);
}